// Round 4
// baseline (16257.942 us; speedup 1.0000x reference)
//
#include <hip/hip_runtime.h>
#include <hip/hip_bf16.h>

#ifndef __has_builtin
#define __has_builtin(x) 0
#endif

#define LSEQ 32768
#define L2E 1.4426950408889634f

// DPP controls
#define DPP_XOR1 0xB1   // quad_perm [1,0,3,2]
#define DPP_XOR2 0x4E   // quad_perm [2,3,0,1]
#define DPP_XOR7 0x141  // row_half_mirror (lane ^ 7 within each 8)
#define DPPF(x, ctrl) __int_as_float(__builtin_amdgcn_update_dpp(0, __float_as_int(x), (ctrl), 0xF, 0xF, true))

typedef _Float16 h2v __attribute__((ext_vector_type(2)));

__device__ __forceinline__ float dot2(int m, int h, float acc) {
#if __has_builtin(__builtin_amdgcn_fdot2)
    return __builtin_amdgcn_fdot2(__builtin_bit_cast(h2v, m),
                                  __builtin_bit_cast(h2v, h), acc, false);
#else
    h2v mm = __builtin_bit_cast(h2v, m), hh = __builtin_bit_cast(h2v, h);
    return fmaf((float)mm[0], (float)hh[0], fmaf((float)mm[1], (float)hh[1], acc));
#endif
}

// ---------------- P1: xm[v][j] = b_im[j] + sum_e w_im[j,e]*emb[v,e] ----------------
__global__ void precompute_xm(const float* __restrict__ emb,
                              const float* __restrict__ w_im,
                              const float* __restrict__ b_im,
                              float* __restrict__ xmws) {
    int tid = (int)threadIdx.x;  // 384 threads: v = tid>>6, j = tid&63
    int v = tid >> 6, j = tid & 63;
    float acc = b_im[j];
    for (int e = 0; e < 32; ++e) acc = fmaf(w_im[j * 32 + e], emb[v * 32 + e], acc);
    xmws[v * 64 + j] = acc;
}

// ---------------- P2: M_v = s_r * W_hh . diag(xm_v) . W_hm  → packed f16 -----------
// Main-kernel lane tid = w*64 + jg*8 + gt*2 + hf  (ch=r&63, gt=r>>6, w=ch>>3, jg=ch&7)
// Lane's 32-half arm = cols [hf*32, hf*32+32) of row r, dword i holds cols (2i,2i+1).
// Stored at Mh[(((v*4+q)*512 + tid)*4 + c] with q=i>>2, c=i&3 (int4-coalesced).
__global__ void precompute_M(const float* __restrict__ emb,
                             const float* __restrict__ w_hm,
                             const float* __restrict__ b_hm,
                             const float* __restrict__ W_ih,
                             const float* __restrict__ b_ih,
                             const float* __restrict__ W_hh,
                             const float* __restrict__ b_hh,
                             const float* __restrict__ xmws,
                             unsigned int* __restrict__ Mh,
                             float* __restrict__ biasws) {
    int n = blockIdx.x * 256 + (int)threadIdx.x;  // 0..49151 = 6*256*32
    int v = n >> 13;
    int rem = n & 8191;
    int r = rem >> 5;
    int kp = rem & 31;        // half-pair index; k0 = 2*kp
    int k0 = kp * 2;
    int gt = r >> 6;
    float s = (gt == 2) ? (-2.0f * L2E) : (-L2E);
    float acc0 = 0.0f, acc1 = 0.0f;
    for (int jj = 0; jj < 64; ++jj) {
        float wx = W_hh[r * 64 + jj] * xmws[v * 64 + jj];
        acc0 = fmaf(wx, w_hm[jj * 64 + k0], acc0);
        acc1 = fmaf(wx, w_hm[jj * 64 + k0 + 1], acc1);
    }
    int ch = r & 63, w = ch >> 3, jg = ch & 7;
    int hf = k0 >> 5;
    int tid = w * 64 + jg * 8 + gt * 2 + hf;
    int i = kp & 15, q = i >> 2, c = i & 3;
    unsigned lo = (unsigned)__builtin_bit_cast(unsigned short, (_Float16)(s * acc0));
    unsigned hi = (unsigned)__builtin_bit_cast(unsigned short, (_Float16)(s * acc1));
    Mh[((v * 4 + q) * 512 + tid) * 4 + c] = lo | (hi << 16);
    if (kp == 0) {  // hf==0 lane: full bias (prescaled)
        float b = b_ih[r] + b_hh[r];
        for (int e = 0; e < 32; ++e) b = fmaf(W_ih[r * 32 + e], emb[v * 32 + e], b);
        for (int jj = 0; jj < 64; ++jj)
            b = fmaf(W_hh[r * 64 + jj] * xmws[v * 64 + jj], b_hm[jj], b);
        biasws[v * 512 + tid] = s * b;
    }
    if (kp == 16) biasws[v * 512 + tid] = 0.0f;  // hf==1 lane: zero
}

// ---------------- main serial kernel: 1 workgroup, 8 waves, channel-grouped -------
// Per step: 4 ds_read_b128 (h as f16) -> 16 v_dot2_f32_f16 -> DPP xor1 half-combine
// -> exp2/rcp activation -> 3 DPP gate butterfly + 8 cndmask -> c/h update ->
// 1 ds_write_b16 -> lgkmcnt(0)+raw s_barrier (NO vmcnt drain: M prefetch for t+2
// stays in flight across the barrier; liveness pins stop the compiler sinking it).
__global__ __launch_bounds__(512, 2) void mlstm_main(
    const int* __restrict__ seq,
    const int4* __restrict__ Mi4,
    const float* __restrict__ biasws,
    const float* __restrict__ W_out,
    const float* __restrict__ b_out,
    float* __restrict__ out)
{
    const int tid = (int)threadIdx.x;
    const int l = tid & 63;
    const int w = tid >> 6;
    const int hf = l & 1;
    const int p = (l >> 1) & 3;       // gate: 0=i 1=f 2=g 3=o
    const int ch = w * 8 + (l >> 3);  // this lane's channel
    const bool gb0 = (p & 1) != 0;
    const bool gb1 = (p & 2) != 0;
    const bool is_g = (p == 2);
    const float act_s = is_g ? 2.0f : 1.0f;
    const float act_b = is_g ? -1.0f : 0.0f;

    __shared__ __align__(16) unsigned short hbuf[2][64];
    __shared__ float cvec[64];

    if (tid < 64) hbuf[1][tid] = 0;

    // seq pipeline: pp0..pp7 = seq[t+2 .. t+9]
    int v0 = seq[0], v1 = seq[1];
    int pp0 = seq[2], pp1 = seq[3], pp2 = seq[4], pp3 = seq[5],
        pp4 = seq[6], pp5 = seq[7], pp6 = seq[8], pp7 = seq[9];

    // prime double buffer: A = arm(v0), B = arm(v1)
    int4 a0 = Mi4[(v0 * 4 + 0) * 512 + tid], a1 = Mi4[(v0 * 4 + 1) * 512 + tid],
         a2 = Mi4[(v0 * 4 + 2) * 512 + tid], a3 = Mi4[(v0 * 4 + 3) * 512 + tid];
    float ba = biasws[v0 * 512 + tid];
    int4 e0 = Mi4[(v1 * 4 + 0) * 512 + tid], e1 = Mi4[(v1 * 4 + 1) * 512 + tid],
         e2 = Mi4[(v1 * 4 + 2) * 512 + tid], e3 = Mi4[(v1 * 4 + 3) * 512 + tid];
    float be = biasws[v1 * 512 + tid];

    float cc = 0.0f;
    __syncthreads();

// PIN(x): liveness use — forces the load producing x to complete here, not sink past.
#define PIN5(X0, X1, X2, X3, XB) \
    asm volatile("" :: "v"(X0.x), "v"(X1.x), "v"(X2.x), "v"(X3.x), "v"(XB))

#define BODY(A0, A1, A2, A3, BA, VN, RB, WB, P0, P1, P2, P3, PB) do {                \
    const int4* hb_ = (const int4*)(&hbuf[RB][hf << 5]);                             \
    int4 H0_ = hb_[0], H1_ = hb_[1], H2_ = hb_[2], H3_ = hb_[3];                     \
    float q0_ = BA, q1_ = 0.0f, q2_ = 0.0f, q3_ = 0.0f;                              \
    q0_ = dot2(A0.x, H0_.x, q0_); q1_ = dot2(A0.y, H0_.y, q1_);                      \
    q2_ = dot2(A0.z, H0_.z, q2_); q3_ = dot2(A0.w, H0_.w, q3_);                      \
    q0_ = dot2(A1.x, H1_.x, q0_); q1_ = dot2(A1.y, H1_.y, q1_);                      \
    q2_ = dot2(A1.z, H1_.z, q2_); q3_ = dot2(A1.w, H1_.w, q3_);                      \
    q0_ = dot2(A2.x, H2_.x, q0_); q1_ = dot2(A2.y, H2_.y, q1_);                      \
    q2_ = dot2(A2.z, H2_.z, q2_); q3_ = dot2(A2.w, H2_.w, q3_);                      \
    q0_ = dot2(A3.x, H3_.x, q0_); q1_ = dot2(A3.y, H3_.y, q1_);                      \
    q2_ = dot2(A3.z, H3_.z, q2_); q3_ = dot2(A3.w, H3_.w, q3_);                      \
    A0 = Mi4[((VN) * 4 + 0) * 512 + tid]; A1 = Mi4[((VN) * 4 + 1) * 512 + tid];      \
    A2 = Mi4[((VN) * 4 + 2) * 512 + tid]; A3 = Mi4[((VN) * 4 + 3) * 512 + tid];      \
    BA = biasws[(VN) * 512 + tid];                                                   \
    float acc_ = (q0_ + q1_) + (q2_ + q3_);                                          \
    float full_ = acc_ + DPPF(acc_, DPP_XOR1);                                       \
    float sg_ = __builtin_amdgcn_rcpf(1.0f + __builtin_amdgcn_exp2f(full_));         \
    float V_ = fmaf(act_s, sg_, act_b);                                              \
    float W_ = DPPF(V_, DPP_XOR2);                                                   \
    float X_ = DPPF(V_, DPP_XOR7);                                                   \
    float Y_ = DPPF(W_, DPP_XOR7);                                                   \
    float t0_ = gb0 ? W_ : V_, t1_ = gb0 ? X_ : Y_;                                  \
    float u0_ = gb0 ? V_ : W_, u1_ = gb0 ? Y_ : X_;                                  \
    float gi_ = gb1 ? t1_ : t0_, gf_ = gb1 ? u1_ : u0_;                              \
    float gg_ = gb1 ? t0_ : t1_, go_ = gb1 ? u0_ : u1_;                              \
    cc = fmaf(gf_, cc, gi_ * gg_);                                                   \
    float tc_ = fmaf(2.0f,                                                           \
        __builtin_amdgcn_rcpf(1.0f + __builtin_amdgcn_exp2f(cc * (-2.0f * L2E))),    \
        -1.0f);                                                                      \
    float hh_ = go_ * tc_;                                                           \
    if ((l & 7) == 0)                                                                \
        hbuf[WB][ch] = __builtin_bit_cast(unsigned short, (_Float16)hh_);            \
    PIN5(P0, P1, P2, P3, PB);   /* other buffer's loads must be done by here */      \
    asm volatile("s_waitcnt lgkmcnt(0)" ::: "memory");                               \
    __builtin_amdgcn_s_barrier();                                                    \
    asm volatile("" ::: "memory");                                                   \
    __builtin_amdgcn_sched_barrier(0);                                               \
} while (0)

    for (int t = 0; t < LSEQ; t += 2) {
        // even step t: reads hbuf[1], writes hbuf[0]; loads arm(pp0) into a-buf;
        //              pins e-buf (loaded last iteration's odd body)
        BODY(a0, a1, a2, a3, ba, pp0, 1, 0, e0, e1, e2, e3, be);
        // odd step t+1: pins a-buf (loaded just above, ~1 body of slack)
        BODY(e0, e1, e2, e3, be, pp1, 0, 1, a0, a1, a2, a3, ba);
        pp0 = pp2; pp1 = pp3; pp2 = pp4; pp3 = pp5; pp4 = pp6; pp5 = pp7;
        int i8 = t + 10; i8 = i8 < LSEQ ? i8 : LSEQ - 1;
        int i9 = t + 11; i9 = i9 < LSEQ ? i9 : LSEQ - 1;
        pp6 = seq[i8]; pp7 = seq[i9];
    }
#undef BODY
#undef PIN5

    if ((l & 7) == 0) cvec[ch] = cc;
    __syncthreads();
    if (tid < 8) {
        float sacc = b_out[tid];
        for (int k2 = 0; k2 < 64; ++k2)
            sacc = fmaf(W_out[tid * 64 + k2], cvec[k2], sacc);
        out[tid] = sacc;
    }
}

extern "C" void kernel_launch(void* const* d_in, const int* in_sizes, int n_in,
                              void* d_out, int out_size, void* d_ws, size_t ws_size,
                              hipStream_t stream) {
    const int*   seq   = (const int*)d_in[0];
    const float* emb   = (const float*)d_in[1];
    const float* w_im  = (const float*)d_in[2];
    const float* b_im  = (const float*)d_in[3];
    const float* w_hm  = (const float*)d_in[4];
    const float* b_hm  = (const float*)d_in[5];
    const float* W_ih  = (const float*)d_in[6];
    const float* b_ih  = (const float*)d_in[7];
    const float* W_hh  = (const float*)d_in[8];
    const float* b_hh  = (const float*)d_in[9];
    const float* W_out = (const float*)d_in[10];
    const float* b_out = (const float*)d_in[11];
    float* out = (float*)d_out;

    float* ws     = (float*)d_ws;
    float* xmws   = ws;                              // 384 floats
    float* biasws = ws + 384;                        // 3072 floats
    unsigned int* Mh = (unsigned int*)(ws + 3456);   // 49152 dwords (13824 B offset, 16B-aligned)

    precompute_xm<<<1, 384, 0, stream>>>(emb, w_im, b_im, xmws);
    precompute_M<<<192, 256, 0, stream>>>(emb, w_hm, b_hm, W_ih, b_ih,
                                          W_hh, b_hh, xmws, Mh, biasws);
    mlstm_main<<<1, 512, 0, stream>>>(seq, (const int4*)Mh, biasws, W_out, b_out, out);
}

// Round 5
// 14773.038 us; speedup vs baseline: 1.1005x; 1.1005x over previous
//
#include <hip/hip_runtime.h>
#include <hip/hip_bf16.h>

#ifndef __has_builtin
#define __has_builtin(x) 0
#endif

#define LSEQ 32768
#define L2E 1.4426950408889634f

// DPP controls
#define DPP_XOR1 0xB1   // quad_perm [1,0,3,2]
#define DPP_XOR2 0x4E   // quad_perm [2,3,0,1]
#define DPP_XOR7 0x141  // row_half_mirror (lane ^ 7 within each 8)
#define DPPF(x, ctrl) __int_as_float(__builtin_amdgcn_update_dpp(0, __float_as_int(x), (ctrl), 0xF, 0xF, true))

typedef _Float16 h2v __attribute__((ext_vector_type(2)));

__device__ __forceinline__ float dot2(int m, int h, float acc) {
#if __has_builtin(__builtin_amdgcn_fdot2)
    return __builtin_amdgcn_fdot2(__builtin_bit_cast(h2v, m),
                                  __builtin_bit_cast(h2v, h), acc, false);
#else
    h2v mm = __builtin_bit_cast(h2v, m), hh = __builtin_bit_cast(h2v, h);
    return fmaf((float)mm[0], (float)hh[0], fmaf((float)mm[1], (float)hh[1], acc));
#endif
}

// ---------------- P1: xm[v][j] = b_im[j] + sum_e w_im[j,e]*emb[v,e] ----------------
__global__ void precompute_xm(const float* __restrict__ emb,
                              const float* __restrict__ w_im,
                              const float* __restrict__ b_im,
                              float* __restrict__ xmws) {
    int tid = (int)threadIdx.x;  // 384 threads: v = tid>>6, j = tid&63
    int v = tid >> 6, j = tid & 63;
    float acc = b_im[j];
    for (int e = 0; e < 32; ++e) acc = fmaf(w_im[j * 32 + e], emb[v * 32 + e], acc);
    xmws[v * 64 + j] = acc;
}

// ---------------- P2: M_v = s_r * W_hh . diag(xm_v) . W_hm  → packed f16 -----------
// Main-kernel lane tid = w*64 + jg*8 + gt*2 + hf  (ch=r&63, gt=r>>6, w=ch>>3, jg=ch&7)
// Lane's 32-half arm = cols [hf*32, hf*32+32) of row r, dword i holds cols (2i,2i+1).
// Stored at Mh[((v*4+q)*512 + tid)*4 + c] with q=i>>2, c=i&3 (int4-coalesced).
__global__ void precompute_M(const float* __restrict__ emb,
                             const float* __restrict__ w_hm,
                             const float* __restrict__ b_hm,
                             const float* __restrict__ W_ih,
                             const float* __restrict__ b_ih,
                             const float* __restrict__ W_hh,
                             const float* __restrict__ b_hh,
                             const float* __restrict__ xmws,
                             unsigned int* __restrict__ Mh,
                             float* __restrict__ biasws) {
    int n = blockIdx.x * 256 + (int)threadIdx.x;  // 0..49151 = 6*256*32
    int v = n >> 13;
    int rem = n & 8191;
    int r = rem >> 5;
    int kp = rem & 31;        // half-pair index; k0 = 2*kp
    int k0 = kp * 2;
    int gt = r >> 6;
    float s = (gt == 2) ? (-2.0f * L2E) : (-L2E);
    float acc0 = 0.0f, acc1 = 0.0f;
    for (int jj = 0; jj < 64; ++jj) {
        float wx = W_hh[r * 64 + jj] * xmws[v * 64 + jj];
        acc0 = fmaf(wx, w_hm[jj * 64 + k0], acc0);
        acc1 = fmaf(wx, w_hm[jj * 64 + k0 + 1], acc1);
    }
    int ch = r & 63, w = ch >> 3, jg = ch & 7;
    int hf = k0 >> 5;
    int tid = w * 64 + jg * 8 + gt * 2 + hf;
    int i = kp & 15, q = i >> 2, c = i & 3;
    unsigned lo = (unsigned)__builtin_bit_cast(unsigned short, (_Float16)(s * acc0));
    unsigned hi = (unsigned)__builtin_bit_cast(unsigned short, (_Float16)(s * acc1));
    Mh[((v * 4 + q) * 512 + tid) * 4 + c] = lo | (hi << 16);
    if (kp == 0) {  // hf==0 lane: full bias (prescaled)
        float b = b_ih[r] + b_hh[r];
        for (int e = 0; e < 32; ++e) b = fmaf(W_ih[r * 32 + e], emb[v * 32 + e], b);
        for (int jj = 0; jj < 64; ++jj)
            b = fmaf(W_hh[r * 64 + jj] * xmws[v * 64 + jj], b_hm[jj], b);
        biasws[v * 512 + tid] = s * b;
    }
    if (kp == 16) biasws[v * 512 + tid] = 0.0f;  // hf==1 lane: zero
}

// ---- AGPR force: M lives in 96 AGPRs per lane; reads/writes via explicit asm ----
#define AWR(DST, SRC) asm volatile("v_accvgpr_write_b32 %0, %1" : "=a"(DST) : "v"(SRC));
#define ARD(SRC, DST) asm volatile("v_accvgpr_read_b32 %0, %1" : "=v"(DST) : "a"(SRC));

#define MDECL(V) int m##V##_0, m##V##_1, m##V##_2, m##V##_3, m##V##_4, m##V##_5, \
                     m##V##_6, m##V##_7, m##V##_8, m##V##_9, m##V##_10, m##V##_11, \
                     m##V##_12, m##V##_13, m##V##_14, m##V##_15;

#define MLOAD(V) { \
    int4 t0_ = Mi4[((V)*4+0)*512+tid], t1_ = Mi4[((V)*4+1)*512+tid], \
         t2_ = Mi4[((V)*4+2)*512+tid], t3_ = Mi4[((V)*4+3)*512+tid]; \
    AWR(m##V##_0,  t0_.x) AWR(m##V##_1,  t0_.y) AWR(m##V##_2,  t0_.z) AWR(m##V##_3,  t0_.w) \
    AWR(m##V##_4,  t1_.x) AWR(m##V##_5,  t1_.y) AWR(m##V##_6,  t1_.z) AWR(m##V##_7,  t1_.w) \
    AWR(m##V##_8,  t2_.x) AWR(m##V##_9,  t2_.y) AWR(m##V##_10, t2_.z) AWR(m##V##_11, t2_.w) \
    AWR(m##V##_12, t3_.x) AWR(m##V##_13, t3_.y) AWR(m##V##_14, t3_.z) AWR(m##V##_15, t3_.w) }

#define ARMV(V) { \
    ARD(m##V##_0,  r0_)  ARD(m##V##_1,  r1_)  ARD(m##V##_2,  r2_)  ARD(m##V##_3,  r3_)  \
    ARD(m##V##_4,  r4_)  ARD(m##V##_5,  r5_)  ARD(m##V##_6,  r6_)  ARD(m##V##_7,  r7_)  \
    ARD(m##V##_8,  r8_)  ARD(m##V##_9,  r9_)  ARD(m##V##_10, r10_) ARD(m##V##_11, r11_) \
    ARD(m##V##_12, r12_) ARD(m##V##_13, r13_) ARD(m##V##_14, r14_) ARD(m##V##_15, r15_) \
    bv_ = biasR##V; }

// ---------------- main serial kernel: 1 workgroup, 8 waves, channel-grouped -------
// Loop memory ops: 4 ds_read_b128 (h) + 1 ds_read_b32 (seq ring) + 1 ds_write_b16.
// M: 96 AGPRs/lane, fetched per step with 16 v_accvgpr_read under uniform switch.
// seq: 2x2048 LDS ring, refilled every 2048 steps via per-lane int4 loads (vmcnt,
// amortized). No global/SMEM ops in steady state -> __syncthreads drain is free.
__global__ __launch_bounds__(512, 2) void mlstm_main(
    const int* __restrict__ seq,
    const int4* __restrict__ Mi4,
    const float* __restrict__ biasws,
    const float* __restrict__ W_out,
    const float* __restrict__ b_out,
    float* __restrict__ out)
{
    const int tid = (int)threadIdx.x;
    const int l = tid & 63;
    const int w = tid >> 6;
    const int hf = l & 1;
    const int p = (l >> 1) & 3;       // gate: 0=i 1=f 2=g 3=o
    const int ch = w * 8 + (l >> 3);  // this lane's channel
    const bool gb0 = (p & 1) != 0;
    const bool gb1 = (p & 2) != 0;
    const bool is_g = (p == 2);
    const float act_s = is_g ? 2.0f : 1.0f;
    const float act_b = is_g ? -1.0f : 0.0f;

    __shared__ __align__(16) unsigned short hbuf[2][64];
    __shared__ float cvec[64];
    __shared__ __align__(16) int seq_c[2][2048];

    // ---- M -> AGPRs (96/lane), bias -> 6 VGPRs ----
    MDECL(0) MDECL(1) MDECL(2) MDECL(3) MDECL(4) MDECL(5)
    MLOAD(0) MLOAD(1) MLOAD(2) MLOAD(3) MLOAD(4) MLOAD(5)
    float biasR0 = biasws[0 * 512 + tid], biasR1 = biasws[1 * 512 + tid],
          biasR2 = biasws[2 * 512 + tid], biasR3 = biasws[3 * 512 + tid],
          biasR4 = biasws[4 * 512 + tid], biasR5 = biasws[5 * 512 + tid];

    // ---- stage seq chunk 0; prime v pipeline from global ----
    const int4* seq4 = (const int4*)seq;
    ((int4*)&seq_c[0][0])[tid] = seq4[tid];
    int vA = seq[0], vB = seq[1];

    if (tid < 64) hbuf[1][tid] = 0;
    float cc = 0.0f;
    __syncthreads();

#define BODY(VCUR, RB, WB, NIDX) do {                                                \
    const int4* hb_ = (const int4*)(&hbuf[RB][hf << 5]);                             \
    int4 H0_ = hb_[0], H1_ = hb_[1], H2_ = hb_[2], H3_ = hb_[3];                     \
    int r0_, r1_, r2_, r3_, r4_, r5_, r6_, r7_,                                      \
        r8_, r9_, r10_, r11_, r12_, r13_, r14_, r15_;                                \
    float bv_;                                                                       \
    switch (__builtin_amdgcn_readfirstlane(VCUR)) {                                  \
        case 0: ARMV(0) break;                                                       \
        case 1: ARMV(1) break;                                                       \
        case 2: ARMV(2) break;                                                       \
        case 3: ARMV(3) break;                                                       \
        case 4: ARMV(4) break;                                                       \
        default: ARMV(5) break;                                                      \
    }                                                                                \
    { int ni_ = (NIDX) < LSEQ ? (NIDX) : (LSEQ - 1);                                 \
      VCUR = seq_c[(ni_ >> 11) & 1][ni_ & 2047]; }                                   \
    float q0_ = dot2(r0_,  H0_.x, bv_),  q1_ = dot2(r1_,  H0_.y, 0.0f);              \
    float q2_ = dot2(r2_,  H0_.z, 0.0f), q3_ = dot2(r3_,  H0_.w, 0.0f);              \
    q0_ = dot2(r4_,  H1_.x, q0_); q1_ = dot2(r5_,  H1_.y, q1_);                      \
    q2_ = dot2(r6_,  H1_.z, q2_); q3_ = dot2(r7_,  H1_.w, q3_);                      \
    q0_ = dot2(r8_,  H2_.x, q0_); q1_ = dot2(r9_,  H2_.y, q1_);                      \
    q2_ = dot2(r10_, H2_.z, q2_); q3_ = dot2(r11_, H2_.w, q3_);                      \
    q0_ = dot2(r12_, H3_.x, q0_); q1_ = dot2(r13_, H3_.y, q1_);                      \
    q2_ = dot2(r14_, H3_.z, q2_); q3_ = dot2(r15_, H3_.w, q3_);                      \
    float acc_ = (q0_ + q1_) + (q2_ + q3_);                                          \
    float full_ = acc_ + DPPF(acc_, DPP_XOR1);                                       \
    float sg_ = __builtin_amdgcn_rcpf(1.0f + __builtin_amdgcn_exp2f(full_));         \
    float V_ = fmaf(act_s, sg_, act_b);                                              \
    float W_ = DPPF(V_, DPP_XOR2);                                                   \
    float X_ = DPPF(V_, DPP_XOR7);                                                   \
    float Y_ = DPPF(W_, DPP_XOR7);                                                   \
    float t0_ = gb0 ? W_ : V_, t1_ = gb0 ? X_ : Y_;                                  \
    float u0_ = gb0 ? V_ : W_, u1_ = gb0 ? Y_ : X_;                                  \
    float gi_ = gb1 ? t1_ : t0_, gf_ = gb1 ? u1_ : u0_;                              \
    float gg_ = gb1 ? t0_ : t1_, go_ = gb1 ? u0_ : u1_;                              \
    cc = fmaf(gf_, cc, gi_ * gg_);                                                   \
    float tc_ = fmaf(2.0f,                                                           \
        __builtin_amdgcn_rcpf(1.0f + __builtin_amdgcn_exp2f(cc * (-2.0f * L2E))),    \
        -1.0f);                                                                      \
    float hh_ = go_ * tc_;                                                           \
    if ((l & 7) == 0)                                                                \
        hbuf[WB][ch] = __builtin_bit_cast(unsigned short, (_Float16)hh_);            \
    __syncthreads();                                                                 \
} while (0)

    for (int t = 0; t < LSEQ; t += 2) {
        if ((t & 2047) == 0) {
            int cb = (t >> 11) + 1;
            if (cb < 16)
                ((int4*)&seq_c[cb & 1][0])[tid] = seq4[cb * 512 + tid];
        }
        BODY(vA, 1, 0, t + 2);   // even step t: reads hbuf[1], writes hbuf[0]
        BODY(vB, 0, 1, t + 3);   // odd step t+1
    }
#undef BODY

    if ((l & 7) == 0) cvec[ch] = cc;
    __syncthreads();
    if (tid < 8) {
        float sacc = b_out[tid];
        for (int k2 = 0; k2 < 64; ++k2)
            sacc = fmaf(W_out[tid * 64 + k2], cvec[k2], sacc);
        out[tid] = sacc;
    }
}

extern "C" void kernel_launch(void* const* d_in, const int* in_sizes, int n_in,
                              void* d_out, int out_size, void* d_ws, size_t ws_size,
                              hipStream_t stream) {
    const int*   seq   = (const int*)d_in[0];
    const float* emb   = (const float*)d_in[1];
    const float* w_im  = (const float*)d_in[2];
    const float* b_im  = (const float*)d_in[3];
    const float* w_hm  = (const float*)d_in[4];
    const float* b_hm  = (const float*)d_in[5];
    const float* W_ih  = (const float*)d_in[6];
    const float* b_ih  = (const float*)d_in[7];
    const float* W_hh  = (const float*)d_in[8];
    const float* b_hh  = (const float*)d_in[9];
    const float* W_out = (const float*)d_in[10];
    const float* b_out = (const float*)d_in[11];
    float* out = (float*)d_out;

    float* ws     = (float*)d_ws;
    float* xmws   = ws;                              // 384 floats
    float* biasws = ws + 384;                        // 3072 floats
    unsigned int* Mh = (unsigned int*)(ws + 3456);   // 49152 dwords (16B-aligned offset)

    precompute_xm<<<1, 384, 0, stream>>>(emb, w_im, b_im, xmws);
    precompute_M<<<192, 256, 0, stream>>>(emb, w_hm, b_hm, W_ih, b_ih,
                                          W_hh, b_hh, xmws, Mh, biasws);
    mlstm_main<<<1, 512, 0, stream>>>(seq, (const int4*)Mh, biasws, W_out, b_out, out);
}

// Round 6
// 14124.672 us; speedup vs baseline: 1.1510x; 1.0459x over previous
//
#include <hip/hip_runtime.h>
#include <hip/hip_bf16.h>

#ifndef __has_builtin
#define __has_builtin(x) 0
#endif

#define LSEQ 32768
#define L2E 1.4426950408889634f

// DPP controls (quad_perm)
#define DPP_XOR1 0xB1   // [1,0,3,2]
#define DPP_XOR2 0x4E   // [2,3,0,1]
#define DPPF(x, ctrl) __int_as_float(__builtin_amdgcn_update_dpp(0, __float_as_int(x), (ctrl), 0xF, 0xF, true))

typedef _Float16 h2v __attribute__((ext_vector_type(2)));

__device__ __forceinline__ float dot2(int m, int h, float acc) {
#if __has_builtin(__builtin_amdgcn_fdot2)
    return __builtin_amdgcn_fdot2(__builtin_bit_cast(h2v, m),
                                  __builtin_bit_cast(h2v, h), acc, false);
#else
    h2v mm = __builtin_bit_cast(h2v, m), hh = __builtin_bit_cast(h2v, h);
    return fmaf((float)mm[0], (float)hh[0], fmaf((float)mm[1], (float)hh[1], acc));
#endif
}

// ---------------- P1: xm[v][j] = b_im[j] + sum_e w_im[j,e]*emb[v,e] ----------------
__global__ void precompute_xm(const float* __restrict__ emb,
                              const float* __restrict__ w_im,
                              const float* __restrict__ b_im,
                              float* __restrict__ xmws) {
    int tid = (int)threadIdx.x;  // 384 threads: v = tid>>6, j = tid&63
    int v = tid >> 6, j = tid & 63;
    float acc = b_im[j];
    for (int e = 0; e < 32; ++e) acc = fmaf(w_im[j * 32 + e], emb[v * 32 + e], acc);
    xmws[v * 64 + j] = acc;
}

// ---------------- P2: M_v = s_r * W_hh . diag(xm_v) . W_hm → packed f16 ------------
// Main kernel: 256 threads. tid256 = w*64 + (ch&15)*4 + ksub, w = ch>>4, ksub = k>>4.
// Lane holds, per v, all 4 gates of channel ch over k-slice [16*ksub,16*ksub+16):
//   gate gt, dword i_dw (k pair) -> int4 q4 = gt*2 + (i_dw>>2), comp c4 = i_dw&3,
//   stored at Mh4[(v*8+q4)*256 + tid256]. Bias per lane: Bws[v*1024 + tid256*4 + gt].
__global__ void precompute_M(const float* __restrict__ emb,
                             const float* __restrict__ w_hm,
                             const float* __restrict__ b_hm,
                             const float* __restrict__ W_ih,
                             const float* __restrict__ b_ih,
                             const float* __restrict__ W_hh,
                             const float* __restrict__ b_hh,
                             const float* __restrict__ xmws,
                             unsigned int* __restrict__ Mh,
                             float* __restrict__ Bws) {
    int n = blockIdx.x * 256 + (int)threadIdx.x;  // 0..49151 = 6*256*32
    int v = n >> 13;
    int rem = n & 8191;
    int r = rem >> 5;
    int kp = rem & 31;        // k pair; k0 = 2*kp
    int k0 = kp * 2;
    int gt = r >> 6;
    float s = (gt == 2) ? (-2.0f * L2E) : (-L2E);
    float acc0 = 0.0f, acc1 = 0.0f;
    for (int jj = 0; jj < 64; ++jj) {
        float wx = W_hh[r * 64 + jj] * xmws[v * 64 + jj];
        acc0 = fmaf(wx, w_hm[jj * 64 + k0], acc0);
        acc1 = fmaf(wx, w_hm[jj * 64 + k0 + 1], acc1);
    }
    int ch = r & 63;
    int w = ch >> 4;
    int ksub = k0 >> 4;
    int tid256 = w * 64 + (ch & 15) * 4 + ksub;
    int i_dw = (k0 & 15) >> 1;
    int q4 = gt * 2 + (i_dw >> 2);
    int c4 = i_dw & 3;
    unsigned lo = (unsigned)__builtin_bit_cast(unsigned short, (_Float16)(s * acc0));
    unsigned hi = (unsigned)__builtin_bit_cast(unsigned short, (_Float16)(s * acc1));
    Mh[((v * 8 + q4) * 256 + tid256) * 4 + c4] = lo | (hi << 16);
    if (i_dw == 0) {  // one thread per (v, r, ksub): bias for this lane+gate
        float b = b_ih[r] + b_hh[r];
        for (int e = 0; e < 32; ++e) b = fmaf(W_ih[r * 32 + e], emb[v * 32 + e], b);
        for (int jj = 0; jj < 64; ++jj)
            b = fmaf(W_hh[r * 64 + jj] * xmws[v * 64 + jj], b_hm[jj], b);
        Bws[v * 1024 + tid256 * 4 + gt] = s * b;
    }
}

// ---- AGPR force: M lives in 192 AGPRs per lane ----
#define AWR(DST, SRC) asm volatile("v_accvgpr_write_b32 %0, %1" : "=a"(DST) : "v"(SRC));
#define ARD(SRC, DST) asm volatile("v_accvgpr_read_b32 %0, %1" : "=v"(DST) : "a"(SRC));

#define MDECL(V) int m##V##_0, m##V##_1, m##V##_2, m##V##_3, m##V##_4, m##V##_5, \
    m##V##_6, m##V##_7, m##V##_8, m##V##_9, m##V##_10, m##V##_11, m##V##_12, \
    m##V##_13, m##V##_14, m##V##_15, m##V##_16, m##V##_17, m##V##_18, m##V##_19, \
    m##V##_20, m##V##_21, m##V##_22, m##V##_23, m##V##_24, m##V##_25, m##V##_26, \
    m##V##_27, m##V##_28, m##V##_29, m##V##_30, m##V##_31;

#define MLOADQ(V, Q) { int4 t_ = Mi4[((V) * 8 + (Q)) * 256 + tid]; \
    AWR(m##V##_##Q##0, t_.x) AWR(m##V##_##Q##1, t_.y) \
    AWR(m##V##_##Q##2, t_.z) AWR(m##V##_##Q##3, t_.w) }
// (names m{V}_{Q}{c} require Q*4+c naming: use explicit macro per Q below)

#define MLOAD(V) { \
    int4 t0_ = Mi4[((V)*8+0)*256+tid], t1_ = Mi4[((V)*8+1)*256+tid], \
         t2_ = Mi4[((V)*8+2)*256+tid], t3_ = Mi4[((V)*8+3)*256+tid], \
         t4_ = Mi4[((V)*8+4)*256+tid], t5_ = Mi4[((V)*8+5)*256+tid], \
         t6_ = Mi4[((V)*8+6)*256+tid], t7_ = Mi4[((V)*8+7)*256+tid]; \
    AWR(m##V##_0,  t0_.x) AWR(m##V##_1,  t0_.y) AWR(m##V##_2,  t0_.z) AWR(m##V##_3,  t0_.w) \
    AWR(m##V##_4,  t1_.x) AWR(m##V##_5,  t1_.y) AWR(m##V##_6,  t1_.z) AWR(m##V##_7,  t1_.w) \
    AWR(m##V##_8,  t2_.x) AWR(m##V##_9,  t2_.y) AWR(m##V##_10, t2_.z) AWR(m##V##_11, t2_.w) \
    AWR(m##V##_12, t3_.x) AWR(m##V##_13, t3_.y) AWR(m##V##_14, t3_.z) AWR(m##V##_15, t3_.w) \
    AWR(m##V##_16, t4_.x) AWR(m##V##_17, t4_.y) AWR(m##V##_18, t4_.z) AWR(m##V##_19, t4_.w) \
    AWR(m##V##_20, t5_.x) AWR(m##V##_21, t5_.y) AWR(m##V##_22, t5_.z) AWR(m##V##_23, t5_.w) \
    AWR(m##V##_24, t6_.x) AWR(m##V##_25, t6_.y) AWR(m##V##_26, t6_.z) AWR(m##V##_27, t6_.w) \
    AWR(m##V##_28, t7_.x) AWR(m##V##_29, t7_.y) AWR(m##V##_30, t7_.z) AWR(m##V##_31, t7_.w) }

#define ARMV(V) { \
    ARD(m##V##_0,  r0_)  ARD(m##V##_1,  r1_)  ARD(m##V##_2,  r2_)  ARD(m##V##_3,  r3_)  \
    ARD(m##V##_4,  r4_)  ARD(m##V##_5,  r5_)  ARD(m##V##_6,  r6_)  ARD(m##V##_7,  r7_)  \
    ARD(m##V##_8,  r8_)  ARD(m##V##_9,  r9_)  ARD(m##V##_10, r10_) ARD(m##V##_11, r11_) \
    ARD(m##V##_12, r12_) ARD(m##V##_13, r13_) ARD(m##V##_14, r14_) ARD(m##V##_15, r15_) \
    ARD(m##V##_16, r16_) ARD(m##V##_17, r17_) ARD(m##V##_18, r18_) ARD(m##V##_19, r19_) \
    ARD(m##V##_20, r20_) ARD(m##V##_21, r21_) ARD(m##V##_22, r22_) ARD(m##V##_23, r23_) \
    ARD(m##V##_24, r24_) ARD(m##V##_25, r25_) ARD(m##V##_26, r26_) ARD(m##V##_27, r27_) \
    ARD(m##V##_28, r28_) ARD(m##V##_29, r29_) ARD(m##V##_30, r30_) ARD(m##V##_31, r31_) \
    bv4_ = bias##V; }

// ---------------- main serial kernel: 1 workgroup, 4 waves (1/SIMD) ---------------
// Lane (256) = w*64 + chl*4 + ksub: channel ch = w*16+chl, k-slice [16ksub,16ksub+16).
// Per step: 2 ds_read_b128 (h f16 slice) -> 32 accvgpr_read (v-switch) -> 32 dot2
// (4 gates x 8) -> quad butterfly (2 DPP stages) -> +bias -> 4 activations ->
// c/h update (quad-redundant) -> 1 ds_write_b16 (ksub==0) -> __syncthreads.
// No VMEM in steady loop (seq via LDS ring) -> barrier's vmcnt drain is free.
__global__ __launch_bounds__(256, 1) void mlstm_main(
    const int* __restrict__ seq,
    const int4* __restrict__ Mi4,
    const float4* __restrict__ Bf4,
    const float* __restrict__ W_out,
    const float* __restrict__ b_out,
    float* __restrict__ out)
{
    const int tid = (int)threadIdx.x;
    const int l = tid & 63;
    const int w = tid >> 6;
    const int ksub = l & 3;
    const int ch = w * 16 + (l >> 2);

    __shared__ __align__(16) unsigned short hbuf[2][64];
    __shared__ float cvec[64];
    __shared__ __align__(16) int seq_c[2][2048];

    // ---- M -> 192 AGPRs/lane; bias -> 6 float4 VGPRs ----
    MDECL(0) MDECL(1) MDECL(2) MDECL(3) MDECL(4) MDECL(5)
    MLOAD(0) MLOAD(1) MLOAD(2) MLOAD(3) MLOAD(4) MLOAD(5)
    float4 bias0 = Bf4[0 * 256 + tid], bias1 = Bf4[1 * 256 + tid],
           bias2 = Bf4[2 * 256 + tid], bias3 = Bf4[3 * 256 + tid],
           bias4 = Bf4[4 * 256 + tid], bias5 = Bf4[5 * 256 + tid];

    // ---- stage seq chunk 0 (2048 ints = 512 int4, 256 threads x2) ----
    const int4* seq4 = (const int4*)seq;
    ((int4*)&seq_c[0][0])[tid]       = seq4[tid];
    ((int4*)&seq_c[0][0])[tid + 256] = seq4[tid + 256];
    int vA = seq[0], vB = seq[1];

    if (tid < 64) hbuf[1][tid] = 0;
    float cc = 0.0f;
    __syncthreads();

#define BODY(VCUR, RB, WB, NIDX) do {                                                \
    const int4* hb_ = (const int4*)(&hbuf[RB][ksub << 4]);                           \
    int4 H0_ = hb_[0], H1_ = hb_[1];                                                 \
    int ni_ = (NIDX) < LSEQ ? (NIDX) : (LSEQ - 1);                                   \
    int vn_ = seq_c[(ni_ >> 11) & 1][ni_ & 2047];                                    \
    int r0_, r1_, r2_, r3_, r4_, r5_, r6_, r7_,                                      \
        r8_, r9_, r10_, r11_, r12_, r13_, r14_, r15_,                                \
        r16_, r17_, r18_, r19_, r20_, r21_, r22_, r23_,                              \
        r24_, r25_, r26_, r27_, r28_, r29_, r30_, r31_;                              \
    float4 bv4_;                                                                     \
    switch (__builtin_amdgcn_readfirstlane(VCUR)) {                                  \
        case 0: ARMV(0) break;                                                       \
        case 1: ARMV(1) break;                                                       \
        case 2: ARMV(2) break;                                                       \
        case 3: ARMV(3) break;                                                       \
        case 4: ARMV(4) break;                                                       \
        default: ARMV(5) break;                                                      \
    }                                                                                \
    VCUR = vn_;                                                                      \
    float a0_ = dot2(r0_,  H0_.x, 0.0f); a0_ = dot2(r1_,  H0_.y, a0_);               \
    a0_ = dot2(r2_,  H0_.z, a0_); a0_ = dot2(r3_,  H0_.w, a0_);                      \
    a0_ = dot2(r4_,  H1_.x, a0_); a0_ = dot2(r5_,  H1_.y, a0_);                      \
    a0_ = dot2(r6_,  H1_.z, a0_); a0_ = dot2(r7_,  H1_.w, a0_);                      \
    float a1_ = dot2(r8_,  H0_.x, 0.0f); a1_ = dot2(r9_,  H0_.y, a1_);               \
    a1_ = dot2(r10_, H0_.z, a1_); a1_ = dot2(r11_, H0_.w, a1_);                      \
    a1_ = dot2(r12_, H1_.x, a1_); a1_ = dot2(r13_, H1_.y, a1_);                      \
    a1_ = dot2(r14_, H1_.z, a1_); a1_ = dot2(r15_, H1_.w, a1_);                      \
    float a2_ = dot2(r16_, H0_.x, 0.0f); a2_ = dot2(r17_, H0_.y, a2_);               \
    a2_ = dot2(r18_, H0_.z, a2_); a2_ = dot2(r19_, H0_.w, a2_);                      \
    a2_ = dot2(r20_, H1_.x, a2_); a2_ = dot2(r21_, H1_.y, a2_);                      \
    a2_ = dot2(r22_, H1_.z, a2_); a2_ = dot2(r23_, H1_.w, a2_);                      \
    float a3_ = dot2(r24_, H0_.x, 0.0f); a3_ = dot2(r25_, H0_.y, a3_);               \
    a3_ = dot2(r26_, H0_.z, a3_); a3_ = dot2(r27_, H0_.w, a3_);                      \
    a3_ = dot2(r28_, H1_.x, a3_); a3_ = dot2(r29_, H1_.y, a3_);                      \
    a3_ = dot2(r30_, H1_.z, a3_); a3_ = dot2(r31_, H1_.w, a3_);                      \
    a0_ += DPPF(a0_, DPP_XOR1); a0_ += DPPF(a0_, DPP_XOR2);                          \
    a1_ += DPPF(a1_, DPP_XOR1); a1_ += DPPF(a1_, DPP_XOR2);                          \
    a2_ += DPPF(a2_, DPP_XOR1); a2_ += DPPF(a2_, DPP_XOR2);                          \
    a3_ += DPPF(a3_, DPP_XOR1); a3_ += DPPF(a3_, DPP_XOR2);                          \
    a0_ += bv4_.x; a1_ += bv4_.y; a2_ += bv4_.z; a3_ += bv4_.w;                      \
    float gi_ = __builtin_amdgcn_rcpf(1.0f + __builtin_amdgcn_exp2f(a0_));           \
    float gf_ = __builtin_amdgcn_rcpf(1.0f + __builtin_amdgcn_exp2f(a1_));           \
    float gg_ = fmaf(2.0f,                                                           \
        __builtin_amdgcn_rcpf(1.0f + __builtin_amdgcn_exp2f(a2_)), -1.0f);           \
    float go_ = __builtin_amdgcn_rcpf(1.0f + __builtin_amdgcn_exp2f(a3_));           \
    cc = fmaf(gf_, cc, gi_ * gg_);                                                   \
    float tc_ = fmaf(2.0f,                                                           \
        __builtin_amdgcn_rcpf(1.0f + __builtin_amdgcn_exp2f(cc * (-2.0f * L2E))),    \
        -1.0f);                                                                      \
    float hh_ = go_ * tc_;                                                           \
    if (ksub == 0)                                                                   \
        hbuf[WB][ch] = __builtin_bit_cast(unsigned short, (_Float16)hh_);            \
    __syncthreads();                                                                 \
} while (0)

    for (int t = 0; t < LSEQ; t += 2) {
        if ((t & 2047) == 0) {
            int cb = (t >> 11) + 1;
            if (cb < 16) {
                int4* dst_ = (int4*)&seq_c[cb & 1][0];
                dst_[tid]       = seq4[cb * 512 + tid];
                dst_[tid + 256] = seq4[cb * 512 + tid + 256];
            }
        }
        BODY(vA, 1, 0, t + 2);   // even step t: reads hbuf[1], writes hbuf[0]
        BODY(vB, 0, 1, t + 3);   // odd step t+1
    }
#undef BODY

    if (ksub == 0) cvec[ch] = cc;
    __syncthreads();
    if (tid < 8) {
        float sacc = b_out[tid];
        for (int k2 = 0; k2 < 64; ++k2)
            sacc = fmaf(W_out[tid * 64 + k2], cvec[k2], sacc);
        out[tid] = sacc;
    }
}

extern "C" void kernel_launch(void* const* d_in, const int* in_sizes, int n_in,
                              void* d_out, int out_size, void* d_ws, size_t ws_size,
                              hipStream_t stream) {
    const int*   seq   = (const int*)d_in[0];
    const float* emb   = (const float*)d_in[1];
    const float* w_im  = (const float*)d_in[2];
    const float* b_im  = (const float*)d_in[3];
    const float* w_hm  = (const float*)d_in[4];
    const float* b_hm  = (const float*)d_in[5];
    const float* W_ih  = (const float*)d_in[6];
    const float* b_ih  = (const float*)d_in[7];
    const float* W_hh  = (const float*)d_in[8];
    const float* b_hh  = (const float*)d_in[9];
    const float* W_out = (const float*)d_in[10];
    const float* b_out = (const float*)d_in[11];
    float* out = (float*)d_out;

    float* ws   = (float*)d_ws;
    float* xmws = ws;                                // 384 floats
    float* Bws  = ws + 384;                          // 6144 floats
    unsigned int* Mh = (unsigned int*)(ws + 6528);   // 49152 dwords (26112 B, 16B-aligned)

    precompute_xm<<<1, 384, 0, stream>>>(emb, w_im, b_im, xmws);
    precompute_M<<<192, 256, 0, stream>>>(emb, w_hm, b_hm, W_ih, b_ih,
                                          W_hh, b_hh, xmws, Mh, Bws);
    mlstm_main<<<1, 256, 0, stream>>>(seq, (const int4*)Mh, (const float4*)Bws,
                                      W_out, b_out, out);
}